// Round 11
// baseline (2837.936 us; speedup 1.0000x reference)
//
#include <hip/hip_runtime.h>
#include <hip/hip_bf16.h>

#define CC 256
#define HH 200
#define WW 200
#define PLANE (HH * WW)       // 40000
#define OUT_H 7
#define OUT_W 7
#define NSP   (OUT_H * OUT_W) // 49
#define NIMG  4
#define NB    1024            // ROIs (fused path requires exactly this)
#define NTILE 10000           // transpose tiles: 4 img * 4 cgrp * 625 ptile
#define TPI   2500            // tiles per image
#define SHBYTES 25088         // max(obuf 25088, tile 16640, skey 4096)

// ---- transpose one 64ch x 64px tile: NCHW fp32 -> NHWC bf16 ----
__device__ __forceinline__ void transpose_tile(
    const float* __restrict__ in, __hip_bfloat16* __restrict__ nhwc,
    char* shraw, int t, int tid)
{
    float (*tile)[65] = (float(*)[65])shraw;   // +1 pad: conflict-free
    int n  = t / TPI;
    int rm = t % TPI;
    int c0 = (rm / 625) * 64;
    int p0 = (rm % 625) * 64;
    int tx = tid & 63, ty = tid >> 6;

    const float* src = in + ((size_t)n * CC + c0) * PLANE + p0;
    #pragma unroll
    for (int i = 0; i < 16; ++i) {
        int c = i * 4 + ty;
        tile[c][tx] = src[(size_t)c * PLANE + tx];
    }
    __syncthreads();
    __hip_bfloat16* dst = nhwc + ((size_t)n * PLANE + p0) * CC + c0;
    #pragma unroll
    for (int i = 0; i < 16; ++i) {
        int p = i * 4 + ty;
        dst[(size_t)p * CC + tx] = __float2bfloat16(tile[tx][p]);
    }
}

// ---- gather one unit (ROI x 128-channel half), R8 body ----
__device__ __forceinline__ void gather_unit(
    const __hip_bfloat16* __restrict__ nhwc, const float* __restrict__ rois,
    const unsigned short* __restrict__ perm, float* __restrict__ out,
    char* shraw, int pos, int tid)
{
    float* obuf = (float*)shraw;               // [128*49]
    int slot = pos >> 1;
    int cg   = pos & 1;
    int b    = (int)perm[slot];
    int q    = tid & 63;
    int wv   = tid >> 6;

    const float* r = rois + b * 5;
    int   bi  = (int)r[0];
    float rx1 = r[1] * 0.25f, ry1 = r[2] * 0.25f;
    float rx2 = r[3] * 0.25f, ry2 = r[4] * 0.25f;
    float bin_w = fmaxf(rx2 - rx1, 1.0f) * (1.0f / OUT_W);
    float bin_h = fmaxf(ry2 - ry1, 1.0f) * (1.0f / OUT_H);

    const __hip_bfloat16* base = nhwc + (size_t)bi * PLANE * CC + cg * 128 + 2 * q;

    int s0 = wv * 13;                          // wave 3 clamps; repeats benign
    #pragma unroll
    for (int k = 0; k < 13; ++k) {
        unsigned s = (unsigned)min(s0 + k, NSP - 1);
        unsigned ph = s / 7u, pw = s % 7u;
        float a0 = 0.f, a1 = 0.f;
        #pragma unroll
        for (int iy = 0; iy < 2; ++iy) {
            float yy = ry1 + ((float)ph + ((float)iy + 0.5f) * 0.5f) * bin_h;
            float py = fminf(fmaxf(yy - 0.5f, 0.0f), (float)(HH - 1));
            int   y0 = min((int)py, HH - 2);
            float fy = py - (float)y0;
            #pragma unroll
            for (int ix = 0; ix < 2; ++ix) {
                float xx = rx1 + ((float)pw + ((float)ix + 0.5f) * 0.5f) * bin_w;
                float px = fminf(fmaxf(xx - 0.5f, 0.0f), (float)(WW - 1));
                int   x0 = min((int)px, WW - 2);
                float fx = px - (float)x0;

                const __hip_bfloat16* p00 = base + (size_t)(y0 * WW + x0) * CC;
                unsigned u00 = *(const unsigned*)(p00);
                unsigned u01 = *(const unsigned*)(p00 + CC);
                unsigned u10 = *(const unsigned*)(p00 + WW * CC);
                unsigned u11 = *(const unsigned*)(p00 + WW * CC + CC);

                float w00 = (1.f - fy) * (1.f - fx);
                float w01 = (1.f - fy) * fx;
                float w10 = fy * (1.f - fx);
                float w11 = fy * fx;

                union { unsigned u; float f; } c;
                c.u = u00 << 16;         a0 += c.f * w00;
                c.u = u00 & 0xFFFF0000u; a1 += c.f * w00;
                c.u = u01 << 16;         a0 += c.f * w01;
                c.u = u01 & 0xFFFF0000u; a1 += c.f * w01;
                c.u = u10 << 16;         a0 += c.f * w10;
                c.u = u10 & 0xFFFF0000u; a1 += c.f * w10;
                c.u = u11 << 16;         a0 += c.f * w11;
                c.u = u11 & 0xFFFF0000u; a1 += c.f * w11;
            }
        }
        obuf[(2 * q + 0) * NSP + s] = a0 * 0.25f;
        obuf[(2 * q + 1) * NSP + s] = a1 * 0.25f;
    }
    __syncthreads();

    float* ob = out + (size_t)b * (CC * NSP) + (size_t)cg * (128 * NSP);
    for (int k = tid; k < 128 * NSP; k += 256)
        __builtin_nontemporal_store(obuf[k], &ob[k]);
}

// ---------- Fused persistent kernel: transpose || gather overlap ----------
// flags layout (ints): [0]=transpose claim  [1..4]=done per image
//                      [5]=perm_ready       [6..13]=per-XCD gather claim
__global__ __launch_bounds__(256) void roialign_fused(
    const float* __restrict__ in, const float* __restrict__ rois,
    __hip_bfloat16* __restrict__ nhwc, unsigned short* __restrict__ perm,
    int* __restrict__ flags, float* __restrict__ out)
{
    __shared__ char shraw[SHBYTES] __attribute__((aligned(16)));
    __shared__ int s_act, s_par;

    int bid = blockIdx.x, tid = threadIdx.x;
    int myxcd = bid & 7;

    volatile int* vq    = (volatile int*)flags;      // [0]
    volatile int* vdone = (volatile int*)flags + 1;  // [1..4]
    volatile int* vpr   = (volatile int*)flags + 5;  // [5]
    volatile int* vqg   = (volatile int*)flags + 6;  // [6..13]

    // ---- block 0: Morton sort (others start transposing immediately) ----
    if (bid == 0) {
        unsigned* skey = (unsigned*)shraw;
        for (int i = tid; i < NB; i += 256) {
            const float* r = rois + i * 5;
            unsigned bi2 = (unsigned)(int)r[0];
            float cx = (r[1] + r[3]) * 0.125f;
            float cy = (r[2] + r[4]) * 0.125f;
            unsigned ix = (unsigned)fminf(fmaxf(cx, 0.f), 255.f);
            unsigned iy = (unsigned)fminf(fmaxf(cy, 0.f), 255.f);
            unsigned m = 0;
            #pragma unroll
            for (int bp = 0; bp < 8; ++bp) {
                m |= ((ix >> bp) & 1u) << (2 * bp);
                m |= ((iy >> bp) & 1u) << (2 * bp + 1);
            }
            skey[i] = (bi2 << 26) | (m << 10) | (unsigned)i;
        }
        __syncthreads();
        for (int size = 2; size <= NB; size <<= 1) {
            for (int stride = size >> 1; stride > 0; stride >>= 1) {
                for (int i = tid; i < NB; i += 256) {
                    int p = i ^ stride;
                    if (p > i) {
                        bool up = ((i & size) == 0);
                        unsigned a = skey[i], b2 = skey[p];
                        if ((a > b2) == up) { skey[i] = b2; skey[p] = a; }
                    }
                }
                __syncthreads();
            }
        }
        for (int i = tid; i < NB; i += 256) perm[i] = (unsigned short)(skey[i] & 1023u);
        __threadfence();
        __syncthreads();
        if (tid == 0) atomicExch((int*)vpr, 1);
        __syncthreads();                     // before shraw reuse
    }

    bool qempty = false;
    while (true) {
        if (tid == 0) {
            int act = -1, par = -1;
            while (act < 0) {
                // 1) gather-ready-first: own XCD chunk, then steal
                if (*vpr) {
                    for (int kk = 0; kk < 8 && act < 0; ++kk) {
                        int k2 = (myxcd + kk) & 7;
                        int idx = vqg[k2];
                        if (idx < 256) {
                            int pos = k2 * 256 + idx;
                            int b   = (int)perm[pos >> 1];
                            int im  = (int)rois[b * 5];
                            if (vdone[im] == TPI) {
                                int got = atomicAdd((int*)(vqg + k2), 1);
                                if (got < 256) {
                                    par = k2 * 256 + got;
                                    // re-check readiness of the unit we actually got
                                    int b2  = (int)perm[par >> 1];
                                    int im2 = (int)rois[b2 * 5];
                                    while (vdone[im2] != TPI)
                                        __builtin_amdgcn_s_sleep(8);
                                    act = 0;
                                }
                            }
                        }
                    }
                }
                // 2) transpose
                if (act < 0 && !qempty) {
                    int t = atomicAdd((int*)vq, 1);
                    if (t < NTILE) { act = 1; par = t; }
                    else qempty = true;
                }
                // 3) exit or spin
                if (act < 0 && qempty) {
                    bool alldone = true;
                    for (int k2 = 0; k2 < 8; ++k2)
                        if (vqg[k2] < 256) { alldone = false; break; }
                    if (alldone) act = 2;
                    else __builtin_amdgcn_s_sleep(32);
                }
            }
            s_act = act; s_par = par;
        }
        __syncthreads();
        int act = s_act, par = s_par;

        if (act == 0) {
            __threadfence();                 // acquire: NHWC data of ready image
            gather_unit(nhwc, rois, perm, out, shraw, par, tid);
        } else if (act == 1) {
            transpose_tile(in, nhwc, shraw, par, tid);
            __threadfence();                 // release: each thread's tile writes
            __syncthreads();
            if (tid == 0) atomicAdd((int*)(vdone + par / TPI), 1);
        } else {
            break;
        }
        __syncthreads();                     // protect shraw reuse next iteration
    }
}

// ---------- Fallback (ws too small / B != 1024): thread-per-output ----------
__global__ __launch_bounds__(256) void roialign_fallback(
    const float* __restrict__ feat, const float* __restrict__ rois,
    float* __restrict__ out, int total)
{
    int idx = blockIdx.x * blockDim.x + threadIdx.x;
    if (idx >= total) return;
    int pw = idx % OUT_W;
    int ph = (idx / OUT_W) % OUT_H;
    int c  = (idx / NSP) % CC;
    int b  = idx / (NSP * CC);

    const float* r = rois + b * 5;
    int   bi  = (int)r[0];
    float rx1 = r[1] * 0.25f, ry1 = r[2] * 0.25f;
    float rx2 = r[3] * 0.25f, ry2 = r[4] * 0.25f;
    float bin_w = fmaxf(rx2 - rx1, 1.0f) * (1.0f / OUT_W);
    float bin_h = fmaxf(ry2 - ry1, 1.0f) * (1.0f / OUT_H);

    const float* fptr = feat + ((size_t)bi * CC + c) * PLANE;
    float acc = 0.0f;
    #pragma unroll
    for (int iy = 0; iy < 2; ++iy) {
        float yy = ry1 + ((float)ph + ((float)iy + 0.5f) * 0.5f) * bin_h;
        float py = fminf(fmaxf(yy - 0.5f, 0.0f), (float)(HH - 1));
        int   y0 = min((int)py, HH - 2);
        float fy = py - (float)y0;
        #pragma unroll
        for (int ix = 0; ix < 2; ++ix) {
            float xx = rx1 + ((float)pw + ((float)ix + 0.5f) * 0.5f) * bin_w;
            float px = fminf(fmaxf(xx - 0.5f, 0.0f), (float)(WW - 1));
            int   x0 = min((int)px, WW - 2);
            float fx = px - (float)x0;
            const float* p = fptr + y0 * WW + x0;
            acc += p[0]      * (1.f - fy) * (1.f - fx)
                 + p[1]      * (1.f - fy) * fx
                 + p[WW]     * fy * (1.f - fx)
                 + p[WW + 1] * fy * fx;
        }
    }
    out[idx] = acc * 0.25f;
}

extern "C" void kernel_launch(void* const* d_in, const int* in_sizes, int n_in,
                              void* d_out, int out_size, void* d_ws, size_t ws_size,
                              hipStream_t stream) {
    const float* feat = (const float*)d_in[0];
    const float* rois = (const float*)d_in[1];
    float* out = (float*)d_out;

    int N = in_sizes[0] / (CC * PLANE);   // 4
    int B = in_sizes[1] / 5;              // 1024

    size_t nhwc_bytes = (size_t)N * PLANE * CC * sizeof(__hip_bfloat16);  // 81,920,000
    size_t flags_off  = nhwc_bytes;                       // 64 B of flags
    size_t perm_off   = nhwc_bytes + 64;
    size_t need       = perm_off + NB * sizeof(unsigned short);

    if (ws_size >= need && B == NB && N == NIMG) {
        __hip_bfloat16* nhwc = (__hip_bfloat16*)d_ws;
        int*            fl   = (int*)((char*)d_ws + flags_off);
        unsigned short* perm = (unsigned short*)((char*)d_ws + perm_off);
        hipMemsetAsync(fl, 0, 64, stream);   // fresh flags every launch (graph-safe)
        roialign_fused<<<dim3(NB), 256, 0, stream>>>(feat, rois, nhwc, perm, fl, out);
    } else {
        int total = out_size;
        roialign_fallback<<<(total + 255) / 256, 256, 0, stream>>>(feat, rois, out, total);
    }
}

// Round 12
// 114.731 us; speedup vs baseline: 24.7355x; 24.7355x over previous
//
#include <hip/hip_runtime.h>
#include <hip/hip_bf16.h>

#define CC 256
#define HH 200
#define WW 200
#define PLANE (HH * WW)       // 40000
#define OUT_H 7
#define OUT_W 7
#define NSP   (OUT_H * OUT_W) // 49
#define NIMG  4
#define NB    1024            // ROIs (pipelined path requires exactly this)
#define TPI   2500            // transpose tiles per image (4 cgrp * 625 ptile)
#define SHBYTES 25088         // max(obuf 25088, tile 16640, skey 4096)

// ---- transpose one 64ch x 64px tile of image n: NCHW fp32 -> NHWC bf16 ----
__device__ __forceinline__ void transpose_tile(
    const float* __restrict__ in, __hip_bfloat16* __restrict__ nhwc,
    char* shraw, int n, int t, int tid)
{
    float (*tile)[65] = (float(*)[65])shraw;   // +1 pad: conflict-free
    int c0 = (t / 625) * 64;
    int p0 = (t % 625) * 64;
    int tx = tid & 63, ty = tid >> 6;

    const float* src = in + ((size_t)n * CC + c0) * PLANE + p0;
    #pragma unroll
    for (int i = 0; i < 16; ++i) {
        int c = i * 4 + ty;
        tile[c][tx] = src[(size_t)c * PLANE + tx];
    }
    __syncthreads();
    __hip_bfloat16* dst = nhwc + ((size_t)n * PLANE + p0) * CC + c0;
    #pragma unroll
    for (int i = 0; i < 16; ++i) {
        int p = i * 4 + ty;
        dst[(size_t)p * CC + tx] = __float2bfloat16(tile[tx][p]);
    }
}

// ---- gather one unit (ROI x 128-channel half): R8/R9 body ----
__device__ __forceinline__ void gather_unit(
    const __hip_bfloat16* __restrict__ nhwc, const float* __restrict__ rois,
    const unsigned short* __restrict__ perm, float* __restrict__ out,
    char* shraw, int u, int tid)
{
    float* obuf = (float*)shraw;               // [128*49]
    int slot = u >> 1;
    int cg   = u & 1;
    int b    = (int)perm[slot];
    int q    = tid & 63;
    int wv   = tid >> 6;

    const float* r = rois + b * 5;
    int   bi  = (int)r[0];
    float rx1 = r[1] * 0.25f, ry1 = r[2] * 0.25f;
    float rx2 = r[3] * 0.25f, ry2 = r[4] * 0.25f;
    float bin_w = fmaxf(rx2 - rx1, 1.0f) * (1.0f / OUT_W);
    float bin_h = fmaxf(ry2 - ry1, 1.0f) * (1.0f / OUT_H);

    const __hip_bfloat16* base = nhwc + (size_t)bi * PLANE * CC + cg * 128 + 2 * q;

    int s0 = wv * 13;                          // wave 3 clamps; repeats benign
    #pragma unroll
    for (int k = 0; k < 13; ++k) {
        unsigned s = (unsigned)min(s0 + k, NSP - 1);
        unsigned ph = s / 7u, pw = s % 7u;
        float a0 = 0.f, a1 = 0.f;
        #pragma unroll
        for (int iy = 0; iy < 2; ++iy) {
            float yy = ry1 + ((float)ph + ((float)iy + 0.5f) * 0.5f) * bin_h;
            float py = fminf(fmaxf(yy - 0.5f, 0.0f), (float)(HH - 1));
            int   y0 = min((int)py, HH - 2);
            float fy = py - (float)y0;
            #pragma unroll
            for (int ix = 0; ix < 2; ++ix) {
                float xx = rx1 + ((float)pw + ((float)ix + 0.5f) * 0.5f) * bin_w;
                float px = fminf(fmaxf(xx - 0.5f, 0.0f), (float)(WW - 1));
                int   x0 = min((int)px, WW - 2);
                float fx = px - (float)x0;

                const __hip_bfloat16* p00 = base + (size_t)(y0 * WW + x0) * CC;
                unsigned u00 = *(const unsigned*)(p00);
                unsigned u01 = *(const unsigned*)(p00 + CC);
                unsigned u10 = *(const unsigned*)(p00 + WW * CC);
                unsigned u11 = *(const unsigned*)(p00 + WW * CC + CC);

                float w00 = (1.f - fy) * (1.f - fx);
                float w01 = (1.f - fy) * fx;
                float w10 = fy * (1.f - fx);
                float w11 = fy * fx;

                union { unsigned uu; float f; } c;
                c.uu = u00 << 16;         a0 += c.f * w00;
                c.uu = u00 & 0xFFFF0000u; a1 += c.f * w00;
                c.uu = u01 << 16;         a0 += c.f * w01;
                c.uu = u01 & 0xFFFF0000u; a1 += c.f * w01;
                c.uu = u10 << 16;         a0 += c.f * w10;
                c.uu = u10 & 0xFFFF0000u; a1 += c.f * w10;
                c.uu = u11 << 16;         a0 += c.f * w11;
                c.uu = u11 & 0xFFFF0000u; a1 += c.f * w11;
            }
        }
        obuf[(2 * q + 0) * NSP + s] = a0 * 0.25f;
        obuf[(2 * q + 1) * NSP + s] = a1 * 0.25f;
    }
    __syncthreads();

    float* ob = out + (size_t)b * (CC * NSP) + (size_t)cg * (128 * NSP);
    for (int k = tid; k < 128 * NSP; k += 256)
        __builtin_nontemporal_store(obuf[k], &ob[k]);
}

// ---------- K1: transpose images 0-1 (5000 tiles) + sort block ----------
__global__ __launch_bounds__(256) void k1_trans01_sort(
    const float* __restrict__ in, __hip_bfloat16* __restrict__ nhwc,
    const float* __restrict__ rois, unsigned short* __restrict__ perm,
    int* __restrict__ ustart)
{
    __shared__ char shraw[SHBYTES] __attribute__((aligned(16)));
    __shared__ int hist[NIMG];
    int bid = blockIdx.x, tid = threadIdx.x;

    if (bid < 2 * TPI) {
        transpose_tile(in, nhwc, shraw, bid / TPI, bid % TPI, tid);
        return;
    }

    // ---- sort block: Morton sort + per-image unit ranges ----
    unsigned* skey = (unsigned*)shraw;
    if (tid < NIMG) hist[tid] = 0;
    __syncthreads();
    for (int i = tid; i < NB; i += 256) {
        const float* r = rois + i * 5;
        unsigned bi2 = (unsigned)(int)r[0];
        atomicAdd(&hist[bi2], 1);
        float cx = (r[1] + r[3]) * 0.125f;     // center * SPATIAL_SCALE
        float cy = (r[2] + r[4]) * 0.125f;
        unsigned ix = (unsigned)fminf(fmaxf(cx, 0.f), 255.f);
        unsigned iy = (unsigned)fminf(fmaxf(cy, 0.f), 255.f);
        unsigned m = 0;
        #pragma unroll
        for (int bp = 0; bp < 8; ++bp) {
            m |= ((ix >> bp) & 1u) << (2 * bp);
            m |= ((iy >> bp) & 1u) << (2 * bp + 1);
        }
        skey[i] = (bi2 << 26) | (m << 10) | (unsigned)i;   // unique keys
    }
    __syncthreads();
    for (int size = 2; size <= NB; size <<= 1) {
        for (int stride = size >> 1; stride > 0; stride >>= 1) {
            for (int i = tid; i < NB; i += 256) {
                int p = i ^ stride;
                if (p > i) {
                    bool up = ((i & size) == 0);
                    unsigned a = skey[i], b2 = skey[p];
                    if ((a > b2) == up) { skey[i] = b2; skey[p] = a; }
                }
            }
            __syncthreads();
        }
    }
    for (int i = tid; i < NB; i += 256) perm[i] = (unsigned short)(skey[i] & 1023u);
    if (tid == 0) {
        int c = 0;
        #pragma unroll
        for (int im = 0; im < NIMG; ++im) { ustart[im] = 2 * c; c += hist[im]; }
        ustart[NIMG] = 2 * c;                  // == 2048
    }
}

// ---------- K2: mixed-role — gather img 0-1 || transpose img 2-3 ----------
// 7-block groups: 2 gather + 5 transpose, so every XCD runs both roles.
__global__ __launch_bounds__(256) void k2_mixed(
    const float* __restrict__ in, __hip_bfloat16* __restrict__ nhwc,
    const float* __restrict__ rois, const unsigned short* __restrict__ perm,
    const int* __restrict__ ustart, float* __restrict__ out)
{
    __shared__ char shraw[SHBYTES] __attribute__((aligned(16)));
    int bid = blockIdx.x, tid = threadIdx.x;
    int g = bid / 7, r = bid % 7;

    if (r < 2) {
        int u = g * 2 + r;                     // 0..2047 across groups
        if (u < ustart[2])                     // units of images 0-1
            gather_unit(nhwc, rois, perm, out, shraw, u, tid);
    } else {
        int t = g * 5 + (r - 2);               // 0..5119
        if (t < 2 * TPI)
            transpose_tile(in, nhwc, shraw, 2 + t / TPI, t % TPI, tid);
    }
}

// ---------- K3: gather img 2-3 ----------
__global__ __launch_bounds__(256) void k3_gather23(
    const __hip_bfloat16* __restrict__ nhwc, const float* __restrict__ rois,
    const unsigned short* __restrict__ perm, const int* __restrict__ ustart,
    float* __restrict__ out)
{
    __shared__ char shraw[SHBYTES] __attribute__((aligned(16)));
    int u = ustart[2] + blockIdx.x;
    if (u < ustart[4])
        gather_unit(nhwc, rois, perm, out, shraw, u, threadIdx.x);
}

// ---------- Fallback (ws too small / shape mismatch): thread-per-output ----------
__global__ __launch_bounds__(256) void roialign_fallback(
    const float* __restrict__ feat, const float* __restrict__ rois,
    float* __restrict__ out, int total)
{
    int idx = blockIdx.x * blockDim.x + threadIdx.x;
    if (idx >= total) return;
    int pw = idx % OUT_W;
    int ph = (idx / OUT_W) % OUT_H;
    int c  = (idx / NSP) % CC;
    int b  = idx / (NSP * CC);

    const float* r = rois + b * 5;
    int   bi  = (int)r[0];
    float rx1 = r[1] * 0.25f, ry1 = r[2] * 0.25f;
    float rx2 = r[3] * 0.25f, ry2 = r[4] * 0.25f;
    float bin_w = fmaxf(rx2 - rx1, 1.0f) * (1.0f / OUT_W);
    float bin_h = fmaxf(ry2 - ry1, 1.0f) * (1.0f / OUT_H);

    const float* fptr = feat + ((size_t)bi * CC + c) * PLANE;
    float acc = 0.0f;
    #pragma unroll
    for (int iy = 0; iy < 2; ++iy) {
        float yy = ry1 + ((float)ph + ((float)iy + 0.5f) * 0.5f) * bin_h;
        float py = fminf(fmaxf(yy - 0.5f, 0.0f), (float)(HH - 1));
        int   y0 = min((int)py, HH - 2);
        float fy = py - (float)y0;
        #pragma unroll
        for (int ix = 0; ix < 2; ++ix) {
            float xx = rx1 + ((float)pw + ((float)ix + 0.5f) * 0.5f) * bin_w;
            float px = fminf(fmaxf(xx - 0.5f, 0.0f), (float)(WW - 1));
            int   x0 = min((int)px, WW - 2);
            float fx = px - (float)x0;
            const float* p = fptr + y0 * WW + x0;
            acc += p[0]      * (1.f - fy) * (1.f - fx)
                 + p[1]      * (1.f - fy) * fx
                 + p[WW]     * fy * (1.f - fx)
                 + p[WW + 1] * fy * fx;
        }
    }
    out[idx] = acc * 0.25f;
}

extern "C" void kernel_launch(void* const* d_in, const int* in_sizes, int n_in,
                              void* d_out, int out_size, void* d_ws, size_t ws_size,
                              hipStream_t stream) {
    const float* feat = (const float*)d_in[0];
    const float* rois = (const float*)d_in[1];
    float* out = (float*)d_out;

    int N = in_sizes[0] / (CC * PLANE);   // 4
    int B = in_sizes[1] / 5;              // 1024

    size_t nhwc_bytes = (size_t)N * PLANE * CC * sizeof(__hip_bfloat16);  // 81,920,000
    size_t perm_off   = nhwc_bytes;
    size_t us_off     = nhwc_bytes + NB * sizeof(unsigned short);
    size_t need       = us_off + (NIMG + 1) * sizeof(int);

    if (ws_size >= need && B == NB && N == NIMG) {
        __hip_bfloat16* nhwc = (__hip_bfloat16*)d_ws;
        unsigned short* perm = (unsigned short*)((char*)d_ws + perm_off);
        int*            us   = (int*)((char*)d_ws + us_off);
        // K1: transpose img 0-1 (5000 one-tile blocks) + 1 sort block
        k1_trans01_sort<<<dim3(2 * TPI + 1), 256, 0, stream>>>(feat, nhwc, rois, perm, us);
        // K2: gather img 0-1  ||  transpose img 2-3 (interleaved roles)
        k2_mixed<<<dim3(7 * 1024), 256, 0, stream>>>(feat, nhwc, rois, perm, us, out);
        // K3: gather img 2-3
        k3_gather23<<<dim3(2 * NB), 256, 0, stream>>>(nhwc, rois, perm, us, out);
    } else {
        int total = out_size;
        roialign_fallback<<<(total + 255) / 256, 256, 0, stream>>>(feat, rois, out, total);
    }
}

// Round 13
// 79.162 us; speedup vs baseline: 35.8496x; 1.4493x over previous
//
#include <hip/hip_runtime.h>
#include <hip/hip_bf16.h>

#define CC 256
#define HH 200
#define WW 200
#define PLANE (HH * WW)       // 40000
#define OUT_H 7
#define OUT_W 7
#define NSP   (OUT_H * OUT_W) // 49
#define BMAX  1024

// ---------- Pass A: NCHW fp32 -> NHWC bf16 transpose; block (0,0,0) also ----------
// ---------- Morton-sorts the ROIs into perm[] (hidden under the transpose) ----------
__global__ __launch_bounds__(256) void nchw2nhwc_bf16_sort(
    const float* __restrict__ in, __hip_bfloat16* __restrict__ out,
    const float* __restrict__ rois, int B, unsigned short* __restrict__ perm)
{
    __shared__ float tile[64][65];     // +1 pad: conflict-free both phases
    __shared__ unsigned skey[BMAX];    // sort scratch (block 0 only)

    int n  = blockIdx.z;
    int c0 = blockIdx.y * 64;
    int p0 = blockIdx.x * 64;
    int tx = threadIdx.x & 63;
    int ty = threadIdx.x >> 6;         // 0..3

    const float* src = in + ((size_t)n * CC + c0) * PLANE + p0;
    #pragma unroll
    for (int i = 0; i < 16; ++i) {
        int c = i * 4 + ty;
        tile[c][tx] = src[(size_t)c * PLANE + tx];   // lanes contiguous along p
    }
    __syncthreads();
    __hip_bfloat16* dst = out + ((size_t)n * PLANE + p0) * CC + c0;
    #pragma unroll
    for (int i = 0; i < 16; ++i) {
        int p = i * 4 + ty;
        dst[(size_t)p * CC + tx] = __float2bfloat16(tile[tx][p]);  // 128 B/wave-store
    }

    if (blockIdx.x == 0 && blockIdx.y == 0 && blockIdx.z == 0) {
        int t = threadIdx.x;
        for (int i = t; i < BMAX; i += 256) {
            unsigned k = 0xFFFFFFFFu;
            if (i < B) {
                const float* r = rois + i * 5;
                unsigned bi = (unsigned)(int)r[0];
                float cx = (r[1] + r[3]) * 0.125f;   // center * SPATIAL_SCALE
                float cy = (r[2] + r[4]) * 0.125f;
                unsigned ix = (unsigned)fminf(fmaxf(cx, 0.f), 255.f);
                unsigned iy = (unsigned)fminf(fmaxf(cy, 0.f), 255.f);
                unsigned m = 0;
                #pragma unroll
                for (int bp = 0; bp < 8; ++bp) {
                    m |= ((ix >> bp) & 1u) << (2 * bp);
                    m |= ((iy >> bp) & 1u) << (2 * bp + 1);
                }
                k = (bi << 26) | (m << 10) | (unsigned)i;
            }
            skey[i] = k;
        }
        __syncthreads();
        for (int size = 2; size <= BMAX; size <<= 1) {
            for (int stride = size >> 1; stride > 0; stride >>= 1) {
                for (int i = t; i < BMAX; i += 256) {
                    int p = i ^ stride;
                    if (p > i) {
                        bool up = ((i & size) == 0);
                        unsigned a = skey[i], b2 = skey[p];
                        if ((a > b2) == up) { skey[i] = b2; skey[p] = a; }
                    }
                }
                __syncthreads();
            }
        }
        for (int i = t; i < BMAX; i += 256) perm[i] = (unsigned short)(skey[i] & 1023u);
    }
}

// ---------- Pass B: 2 blocks per ROI (128 ch each); lane = 2 channels (uint) ----------
// Explicit 2-deep software pipeline: issue all 16 corner loads of sample k+1
// (into reg buffer (k+1)&1), then compute sample k from buffer k&1. All array
// indices static under full unroll -> registers, not scratch.
__global__ __launch_bounds__(256) void roialign_nhwc2_bf16p(
    const __hip_bfloat16* __restrict__ nhwc,    // (N, H, W, C) bf16
    const float* __restrict__ rois,             // (B, 5)
    const unsigned short* __restrict__ perm,    // Morton-sorted roi ids
    float* __restrict__ out)                    // (B, C, 7, 7) fp32
{
    __shared__ float obuf[128 * NSP];  // 25088 B
    int nblk = gridDim.x;              // B*2
    int bid  = blockIdx.x;
    int pos;
    if ((nblk & 7) == 0) { int cpx = nblk >> 3; pos = (bid & 7) * cpx + (bid >> 3); }
    else                 { pos = bid; }
    int slot = pos >> 1;
    int cg   = pos & 1;                // 128-channel half
    int b    = (int)perm[slot];

    int t  = threadIdx.x;
    int q  = t & 63;
    int wv = t >> 6;

    const float* r = rois + b * 5;
    int   bi  = (int)r[0];
    float rx1 = r[1] * 0.25f, ry1 = r[2] * 0.25f;
    float rx2 = r[3] * 0.25f, ry2 = r[4] * 0.25f;
    float bin_w = fmaxf(rx2 - rx1, 1.0f) * (1.0f / OUT_W);
    float bin_h = fmaxf(ry2 - ry1, 1.0f) * (1.0f / OUT_H);

    const __hip_bfloat16* base = nhwc + (size_t)bi * PLANE * CC + cg * 128 + 2 * q;

    int s0 = wv * 13;                  // contiguous chunk; wave 3 clamps (repeats benign)

    unsigned u[2][16];                 // double-buffered corner loads (static idx only)
    float    fyb[2][2], fxb[2][2];     // per-buffer bilinear fractions

    // ---- load sample `s` into buffer `j` (16 independent global loads) ----
    #define LOAD_S(s_, j_)                                                          \
    {                                                                               \
        unsigned s = (unsigned)(s_);                                                \
        unsigned ph = s / 7u, pw = s % 7u;                                          \
        int yrow[2]; int xcol[2];                                                   \
        _Pragma("unroll")                                                           \
        for (int iy = 0; iy < 2; ++iy) {                                            \
            float yy = ry1 + ((float)ph + ((float)iy + 0.5f) * 0.5f) * bin_h;       \
            float py = fminf(fmaxf(yy - 0.5f, 0.0f), (float)(HH - 1));              \
            int   y0 = min((int)py, HH - 2);                                        \
            fyb[j_][iy] = py - (float)y0;                                           \
            yrow[iy] = y0;                                                          \
        }                                                                           \
        _Pragma("unroll")                                                           \
        for (int ix = 0; ix < 2; ++ix) {                                            \
            float xx = rx1 + ((float)pw + ((float)ix + 0.5f) * 0.5f) * bin_w;       \
            float px = fminf(fmaxf(xx - 0.5f, 0.0f), (float)(WW - 1));              \
            int   x0 = min((int)px, WW - 2);                                        \
            fxb[j_][ix] = px - (float)x0;                                           \
            xcol[ix] = x0;                                                          \
        }                                                                           \
        _Pragma("unroll")                                                           \
        for (int iy = 0; iy < 2; ++iy) {                                            \
            _Pragma("unroll")                                                       \
            for (int ix = 0; ix < 2; ++ix) {                                        \
                const __hip_bfloat16* p00 = base + (size_t)(yrow[iy] * WW + xcol[ix]) * CC; \
                int e = (iy * 2 + ix) * 4;                                          \
                u[j_][e + 0] = *(const unsigned*)(p00);                             \
                u[j_][e + 1] = *(const unsigned*)(p00 + CC);                        \
                u[j_][e + 2] = *(const unsigned*)(p00 + WW * CC);                   \
                u[j_][e + 3] = *(const unsigned*)(p00 + WW * CC + CC);              \
            }                                                                       \
        }                                                                           \
    }

    // ---- compute sample `s` from buffer `j`, write obuf ----
    #define COMP_S(s_, j_)                                                          \
    {                                                                               \
        unsigned s = (unsigned)(s_);                                                \
        float a0 = 0.f, a1 = 0.f;                                                   \
        _Pragma("unroll")                                                           \
        for (int iy = 0; iy < 2; ++iy) {                                            \
            _Pragma("unroll")                                                       \
            for (int ix = 0; ix < 2; ++ix) {                                        \
                float fy = fyb[j_][iy], fx = fxb[j_][ix];                           \
                float w00 = (1.f - fy) * (1.f - fx);                                \
                float w01 = (1.f - fy) * fx;                                       \
                float w10 = fy * (1.f - fx);                                       \
                float w11 = fy * fx;                                               \
                int e = (iy * 2 + ix) * 4;                                          \
                union { unsigned uu; float f; } c;                                  \
                c.uu = u[j_][e + 0] << 16;         a0 += c.f * w00;                 \
                c.uu = u[j_][e + 0] & 0xFFFF0000u; a1 += c.f * w00;                 \
                c.uu = u[j_][e + 1] << 16;         a0 += c.f * w01;                 \
                c.uu = u[j_][e + 1] & 0xFFFF0000u; a1 += c.f * w01;                 \
                c.uu = u[j_][e + 2] << 16;         a0 += c.f * w10;                 \
                c.uu = u[j_][e + 2] & 0xFFFF0000u; a1 += c.f * w10;                 \
                c.uu = u[j_][e + 3] << 16;         a0 += c.f * w11;                 \
                c.uu = u[j_][e + 3] & 0xFFFF0000u; a1 += c.f * w11;                 \
            }                                                                       \
        }                                                                           \
        obuf[(2 * q + 0) * NSP + s] = a0 * 0.25f;                                   \
        obuf[(2 * q + 1) * NSP + s] = a1 * 0.25f;                                   \
    }

    LOAD_S(min(s0, NSP - 1), 0)
    #pragma unroll
    for (int k = 0; k < 13; ++k) {
        if (k < 12) LOAD_S(min(s0 + k + 1, NSP - 1), (k + 1) & 1)
        COMP_S(min(s0 + k, NSP - 1), k & 1)
    }
    #undef LOAD_S
    #undef COMP_S

    __syncthreads();

    // Contiguous 6272-float run (not /256 -> runtime-bounded); NT stores:
    // write-once, keep L2 for gathers.
    float* ob = out + (size_t)b * (CC * NSP) + (size_t)cg * (128 * NSP);
    for (int k = t; k < 128 * NSP; k += 256)
        __builtin_nontemporal_store(obuf[k], &ob[k]);
}

// ---------- Fallback (ws too small / B too big): thread-per-output ----------
__global__ __launch_bounds__(256) void roialign_fallback(
    const float* __restrict__ feat, const float* __restrict__ rois,
    float* __restrict__ out, int total)
{
    int idx = blockIdx.x * blockDim.x + threadIdx.x;
    if (idx >= total) return;
    int pw = idx % OUT_W;
    int ph = (idx / OUT_W) % OUT_H;
    int c  = (idx / NSP) % CC;
    int b  = idx / (NSP * CC);

    const float* r = rois + b * 5;
    int   bi  = (int)r[0];
    float rx1 = r[1] * 0.25f, ry1 = r[2] * 0.25f;
    float rx2 = r[3] * 0.25f, ry2 = r[4] * 0.25f;
    float bin_w = fmaxf(rx2 - rx1, 1.0f) * (1.0f / OUT_W);
    float bin_h = fmaxf(ry2 - ry1, 1.0f) * (1.0f / OUT_H);

    const float* fptr = feat + ((size_t)bi * CC + c) * PLANE;
    float acc = 0.0f;
    #pragma unroll
    for (int iy = 0; iy < 2; ++iy) {
        float yy = ry1 + ((float)ph + ((float)iy + 0.5f) * 0.5f) * bin_h;
        float py = fminf(fmaxf(yy - 0.5f, 0.0f), (float)(HH - 1));
        int   y0 = min((int)py, HH - 2);
        float fy = py - (float)y0;
        #pragma unroll
        for (int ix = 0; ix < 2; ++ix) {
            float xx = rx1 + ((float)pw + ((float)ix + 0.5f) * 0.5f) * bin_w;
            float px = fminf(fmaxf(xx - 0.5f, 0.0f), (float)(WW - 1));
            int   x0 = min((int)px, WW - 2);
            float fx = px - (float)x0;
            const float* p = fptr + y0 * WW + x0;
            acc += p[0]      * (1.f - fy) * (1.f - fx)
                 + p[1]      * (1.f - fy) * fx
                 + p[WW]     * fy * (1.f - fx)
                 + p[WW + 1] * fy * fx;
        }
    }
    out[idx] = acc * 0.25f;
}

extern "C" void kernel_launch(void* const* d_in, const int* in_sizes, int n_in,
                              void* d_out, int out_size, void* d_ws, size_t ws_size,
                              hipStream_t stream) {
    const float* feat = (const float*)d_in[0];
    const float* rois = (const float*)d_in[1];
    float* out = (float*)d_out;

    int N = in_sizes[0] / (CC * PLANE);   // 4
    int B = in_sizes[1] / 5;              // 1024

    size_t nhwc_bytes = (size_t)N * PLANE * CC * sizeof(__hip_bfloat16);  // 81,920,000
    size_t need = nhwc_bytes + BMAX * sizeof(unsigned short);

    if (ws_size >= need && B <= BMAX) {
        __hip_bfloat16* nhwc = (__hip_bfloat16*)d_ws;
        unsigned short* perm = (unsigned short*)((char*)d_ws + nhwc_bytes);
        nchw2nhwc_bf16_sort<<<dim3(PLANE / 64, CC / 64, N), 256, 0, stream>>>(
            feat, nhwc, rois, B, perm);
        roialign_nhwc2_bf16p<<<dim3(B * 2), 256, 0, stream>>>(nhwc, rois, perm, out);
    } else {
        int total = out_size;
        roialign_fallback<<<(total + 255) / 256, 256, 0, stream>>>(feat, rois, out, total);
    }
}